// Round 10
// baseline (5678.568 us; speedup 1.0000x reference)
//
#include <hip/hip_runtime.h>
#include <math.h>

#define N_SAMP 4096
#define NS     7
#define DT_F   1e-5f
#define B0_F   80.0f
#define T2_F   1.0f
#define SW_F   1000.0f
#define TWO_PI 6.2831853071795864769f
#define NSWEEP 9
#define NROUND (NSWEEP * 127)   // 1143

// ws layout (floats): H0:0 | cs:16384..162688 | Vt:162688 | lam:179072 | U:179200
//                     M:195584 | W:211968
// cs reuse after jacobi_v: fidf 16384..24576 (float2[4096])
// out (f32, 24576 total): ReFID [0,4096) | time [4096,8192) |
//                         Re shifted spec [8192,16384) | freq [16384,24576)

__device__ __forceinline__ int swz(int r, int c) { return r * 128 + (c ^ (r & 31)); }

__device__ __forceinline__ void pq_of(int t, int j, int& p, int& q) {
    if (j == 0) { p = t; q = 127; }
    else {
        int a = (t + j) % 127;
        int b = (t + 127 - j) % 127;
        p = a < b ? a : b;
        q = a < b ? b : a;
    }
}

__global__ void k_build_h0(const float* __restrict__ h, float* __restrict__ H0) {
    int idx = blockIdx.x * 256 + threadIdx.x;    // 0..16383
    int r = idx >> 7, c = idx & 127;
    float val = 0.f;
    if (r == c) {
        float acc = 0.f;
        for (int i = 0; i < NS; ++i) {
            float zi = ((r >> (6 - i)) & 1) ? -0.5f : 0.5f;
            acc += B0_F * h[i * 7 + i] * zi;
            for (int j = i + 1; j < NS; ++j) {
                float zj = ((r >> (6 - j)) & 1) ? -0.5f : 0.5f;
                acc += h[i * 7 + j] * zi * zj;
            }
        }
        val = TWO_PI * acc;
    } else {
        int x = r ^ c;
        if (__popc(x) == 2) {
            int u = 31 - __clz(x);
            int v = __ffs(x) - 1;
            if (((r >> u) & 1) != ((r >> v) & 1)) {
                int i = 6 - u, j = 6 - v;   // i<j
                val = TWO_PI * 0.5f * h[i * 7 + j];
            }
        }
    }
    H0[idx] = val;
}

__global__ __launch_bounds__(1024) void k_jacobi_a(const float* __restrict__ H0,
                                                   float2* __restrict__ cs_ws,
                                                   float* __restrict__ lam_out) {
    extern __shared__ float A[];
    const int tid = threadIdx.x;
    for (int m = tid; m < 16384; m += 1024) {
        int r = m >> 7, c = m & 127;
        A[swz(r, c)] = H0[m];
    }
    __syncthreads();

    const int jbase = tid >> 7;
    const int k     = tid & 127;

    for (int round = 0; round < NROUND; ++round) {
        const int t = round % 127;
        float cr[8], sr[8];
        int   pr[8], qr[8];
#pragma unroll
        for (int i = 0; i < 8; ++i) {
            int j = jbase + i * 8;
            int p, q; pq_of(t, j, p, q);
            pr[i] = p; qr[i] = q;
            float app = A[swz(p, p)];
            float aqq = A[swz(q, q)];
            float apq = A[swz(p, q)];
            float c, s;
            if (fabsf(apq) < 1e-30f) { c = 1.f; s = 0.f; }
            else {
                float tau = (aqq - app) / (2.f * apq);
                float tt  = copysignf(1.f / (fabsf(tau) + sqrtf(1.f + tau * tau)), tau);
                c = rsqrtf(1.f + tt * tt);
                s = tt * c;
            }
            cr[i] = c; sr[i] = s;
            if (k == 0) cs_ws[round * 64 + j] = make_float2(c, s);
        }
        __syncthreads();
#pragma unroll
        for (int i = 0; i < 8; ++i) {
            int p = pr[i], q = qr[i];
            float c = cr[i], s = sr[i];
            int ip = swz(p, k), iq = swz(q, k);
            float ap = A[ip], aq = A[iq];
            A[ip] = c * ap - s * aq;
            A[iq] = s * ap + c * aq;
        }
        __syncthreads();
#pragma unroll
        for (int i = 0; i < 8; ++i) {
            int p = pr[i], q = qr[i];
            float c = cr[i], s = sr[i];
            int ip = swz(k, p), iq = swz(k, q);
            float ap = A[ip], aq = A[iq];
            A[ip] = c * ap - s * aq;
            A[iq] = s * ap + c * aq;
        }
        __syncthreads();
    }

    if (tid < 128) lam_out[tid] = A[swz(tid, tid)];
}

__global__ __launch_bounds__(1024) void k_jacobi_v(const float2* __restrict__ cs_ws,
                                                   float* __restrict__ Vt_out) {
    extern __shared__ float Vt[];
    const int tid = threadIdx.x;
    for (int m = tid; m < 16384; m += 1024) {
        int r = m >> 7, c = m & 127;
        Vt[swz(r, c)] = (r == c) ? 1.f : 0.f;
    }
    __syncthreads();

    const int jbase = tid >> 7;
    const int k     = tid & 127;

    for (int round = 0; round < NROUND; ++round) {
        const int t = round % 127;
#pragma unroll
        for (int i = 0; i < 8; ++i) {
            int j = jbase + i * 8;
            int p, q; pq_of(t, j, p, q);
            float2 cs = cs_ws[round * 64 + j];
            int ip = swz(p, k), iq = swz(q, k);
            float vp = Vt[ip], vq = Vt[iq];
            Vt[ip] = cs.x * vp - cs.y * vq;
            Vt[iq] = cs.y * vp + cs.x * vq;
        }
        __syncthreads();
    }

    for (int m = tid; m < 16384; m += 1024) {
        int r = m >> 7, c = m & 127;
        Vt_out[m] = Vt[swz(r, c)];
    }
}

__global__ void k_opv(const float* __restrict__ Vt, float* __restrict__ U) {
    int idx = blockIdx.x * 256 + threadIdx.x;
    int b = idx >> 7, r = idx & 127;
    float acc = 0.f;
#pragma unroll
    for (int p = 0; p < 7; ++p)
        if (!((r >> p) & 1)) acc += Vt[b * 128 + r + (1 << p)];
    U[b * 128 + r] = acc;
}

__global__ void k_m(const float* __restrict__ Vt, const float* __restrict__ U,
                    float* __restrict__ M) {
    __shared__ float va[128];
    int a = blockIdx.x, b = threadIdx.x;
    va[b] = Vt[a * 128 + b];
    __syncthreads();
    float acc = 0.f;
    for (int r = 0; r < 128; ++r) acc += va[r] * U[b * 128 + r];
    M[a * 128 + b] = acc;
}

__global__ void k_w(const float* __restrict__ M, float* __restrict__ W) {
    int idx = blockIdx.x * 256 + threadIdx.x;
    int a = idx >> 7, b = idx & 127;
    W[idx] = M[idx] * 0.5f * (M[idx] + M[b * 128 + a]);
}

// FID[n] = apod(n) * sum_ab W[a][b] e^{+i(lam_a-lam_b) t_n}
// full complex to fidf (ws); Re only to out[n] (FID chunk = 4096 floats)
__global__ __launch_bounds__(256) void k_fid(const float* __restrict__ W,
                                             const float* __restrict__ lam,
                                             float2* __restrict__ fidf,
                                             float* __restrict__ out) {
    __shared__ float2 cbuf[128];
    __shared__ float  redr[256], redi[256];
    const int n = blockIdx.x;
    const int tid = threadIdx.x;
    const float t = (float)n * DT_F;
    if (tid < 128) {
        float sn, cs;
        sincosf(lam[tid] * t, &sn, &cs);
        cbuf[tid] = make_float2(cs, -sn);
    }
    __syncthreads();
    float ar = 0.f, ai = 0.f;
    for (int i = 0; i < 64; ++i) {
        int m = i * 256 + tid;
        int a = m >> 7, b = m & 127;
        float w = W[m];
        float2 ca = cbuf[a], cb = cbuf[b];
        ar += w * (ca.x * cb.x + ca.y * cb.y);
        ai += w * (ca.x * cb.y - ca.y * cb.x);
    }
    redr[tid] = ar; redi[tid] = ai;
    __syncthreads();
    for (int s = 128; s > 0; s >>= 1) {
        if (tid < s) { redr[tid] += redr[tid + s]; redi[tid] += redi[tid + s]; }
        __syncthreads();
    }
    if (tid == 0) {
        float ap = expf(-(DT_F / T2_F) * (float)n);
        float re = redr[0] * ap, im = redi[0] * ap;
        fidf[n] = make_float2(re, im);
        out[n] = re;                         // FID chunk: real part
    }
}

// Shifted spectrum, real part only: out[8192+k] = Re( DFT_{K=(k+4096)&8191}(FID) )
__global__ __launch_bounds__(256) void k_dft(const float2* __restrict__ fidf,
                                             float* __restrict__ out) {
    __shared__ float2 fid[4096];
    const int tid = threadIdx.x;
    for (int m = tid; m < 4096; m += 256) fid[m] = fidf[m];
    __syncthreads();
    const int k = blockIdx.x * 256 + tid;       // 0..8191
    const int K = (k + 4096) & 8191;            // fftshift
    const float C = TWO_PI / 8192.0f;
    float ar = 0.f;
    int idx = 0;
    for (int n = 0; n < 4096; ++n) {
        float2 s = fid[n];
        float sn, cs;
        __sincosf(C * (float)idx, &sn, &cs);
        ar += s.x * cs + s.y * sn;              // Re( FID[n] * e^{-i 2pi n K / 8192} )
        idx = (idx + K) & 8191;
    }
    out[8192 + k] = ar;
}

__global__ void k_axes(float* __restrict__ out) {
    int i = blockIdx.x * 256 + threadIdx.x;     // 0..8191
    if (i < N_SAMP)
        out[4096 + i] = (float)i * ((N_SAMP / SW_F) / (float)(N_SAMP - 1));
    if (i < 2 * N_SAMP)
        out[16384 + i] = -0.5f * SW_F + (float)i * (SW_F / (float)(2 * N_SAMP - 1));
}

extern "C" void kernel_launch(void* const* d_in, const int* in_sizes, int n_in,
                              void* d_out, int out_size, void* d_ws, size_t ws_size,
                              hipStream_t stream) {
    const float* h = (const float*)d_in[0];
    float* out = (float*)d_out;
    float* ws  = (float*)d_ws;

    float*  H0   = ws;
    float2* cs   = (float2*)(ws + 16384);
    float*  Vt   = ws + 162688;
    float*  lam  = ws + 179072;
    float*  U    = ws + 179200;
    float*  M    = ws + 195584;
    float*  W    = ws + 211968;
    float2* fidf = (float2*)(ws + 16384);       // cs reuse (dead after jacobi_v)

    k_build_h0<<<64, 256, 0, stream>>>(h, H0);
    k_jacobi_a<<<1, 1024, 65536, stream>>>(H0, cs, lam);
    k_jacobi_v<<<1, 1024, 65536, stream>>>(cs, Vt);
    k_opv<<<64, 256, 0, stream>>>(Vt, U);
    k_m<<<128, 128, 0, stream>>>(Vt, U, M);
    k_w<<<64, 256, 0, stream>>>(M, W);

    k_fid<<<N_SAMP, 256, 0, stream>>>(W, lam, fidf, out);
    k_dft<<<32, 256, 0, stream>>>(fidf, out);
    k_axes<<<32, 256, 0, stream>>>(out);
}

// Round 11
// 1036.023 us; speedup vs baseline: 5.4811x; 5.4811x over previous
//
#include <hip/hip_runtime.h>
#include <math.h>

#define N_SAMP 4096
#define NS     7
#define DT_F   1e-5f
#define B0_F   80.0f
#define T2_F   1.0f
#define SW_F   1000.0f
#define TWO_PI 6.2831853071795864769f
#define NSWEEP_S 8

// ws layout (floats): Vt 0..16384 | lam 16384..16512 | U 16512..32896 |
//                     M 32896..49280 | W 49280..65664 | fidf(float2) 65664..73856
// out (f32, 24576): ReFID [0,4096) | time [4096,8192) |
//                   Re shifted spec [8192,16384) | freq [16384,24576)

// Sector eigensolver: H0 is block-diagonal in popcount sectors (flip-flop terms
// preserve total Sz). 8 blocks, sizes C(7,s) = {1,7,21,35,35,21,7,1}.
// One workgroup (64 threads) per sector; A and V in LDS; cyclic Jacobi.
__global__ __launch_bounds__(64) void k_eig(const float* __restrict__ h,
                                            float* __restrict__ Vt_full,
                                            float* __restrict__ lam_out) {
    const int nsz_[8]   = {1, 7, 21, 35, 35, 21, 7, 1};
    const int nbase_[8] = {0, 1, 8, 29, 64, 99, 120, 127};
    const int s    = blockIdx.x;
    const int ns   = nsz_[s];
    const int base = nbase_[s];
    const int tid  = threadIdx.x;

    __shared__ float As[36 * 37];
    __shared__ float Vs[36 * 37];
    __shared__ int   st[36];
    __shared__ float hs[49];
    __shared__ int   pp[18];
    __shared__ float cc[18], ss[18];

    if (tid < 49) hs[tid] = h[tid];
    if (tid == 0) {
        int cnt = 0;
        for (int r = 0; r < 128; ++r) if (__popc(r) == s) st[cnt++] = r;
    }
    for (int t = tid; t < 36 * 37; t += 64) { As[t] = 0.f; Vs[t] = 0.f; }
    __syncthreads();

    // Build sector Hamiltonian directly from h
    for (int t = tid; t < ns * ns; t += 64) {
        int i = t / ns, j = t % ns;
        int r = st[i], c = st[j];
        float val = 0.f;
        if (r == c) {
            float acc = 0.f;
            for (int a = 0; a < 7; ++a) {
                float za = ((r >> (6 - a)) & 1) ? -0.5f : 0.5f;
                acc += B0_F * hs[a * 7 + a] * za;
                for (int b = a + 1; b < 7; ++b) {
                    float zb = ((r >> (6 - b)) & 1) ? -0.5f : 0.5f;
                    acc += hs[a * 7 + b] * za * zb;
                }
            }
            val = TWO_PI * acc;
        } else {
            int x = r ^ c;
            if (__popc(x) == 2) {
                int u = 31 - __clz(x);
                int v = __ffs(x) - 1;
                if (((r >> u) & 1) != ((r >> v) & 1))
                    val = TWO_PI * 0.5f * hs[(6 - u) * 7 + (6 - v)];
            }
        }
        As[i * 37 + j] = val;
    }
    for (int i = tid; i < ns; i += 64) Vs[i * 37 + i] = 1.f;
    __syncthreads();

    if (ns > 1) {
        const int m      = (ns + 1) & ~1;   // pad to even
        const int nr     = m - 1;
        const int npairs = m / 2;
        for (int sweep = 0; sweep < NSWEEP_S; ++sweep) {
            for (int t = 0; t < nr; ++t) {
                if (tid < npairs) {
                    int p, q;
                    if (tid == 0) { p = t; q = m - 1; }
                    else {
                        int a1 = (t + tid) % nr;
                        int b1 = (t + nr - tid) % nr;
                        p = a1 < b1 ? a1 : b1;
                        q = a1 < b1 ? b1 : a1;
                    }
                    float c = 1.f, sn = 0.f;
                    if (q < ns) {
                        float app = As[p * 37 + p];
                        float aqq = As[q * 37 + q];
                        float apq = As[p * 37 + q];
                        if (fabsf(apq) >= 1e-30f) {
                            float tau = (aqq - app) / (2.f * apq);
                            float tt  = copysignf(1.f / (fabsf(tau) + sqrtf(1.f + tau * tau)), tau);
                            c  = rsqrtf(1.f + tt * tt);
                            sn = tt * c;
                        }
                    }
                    pp[tid] = (p << 8) | q;
                    cc[tid] = c; ss[tid] = sn;
                }
                __syncthreads();
                // row phase: rotate rows of A and V
                for (int w = tid; w < npairs * ns; w += 64) {
                    int j = w / ns, k = w % ns;
                    int pq = pp[j]; int p = pq >> 8, q = pq & 255;
                    float c = cc[j], sn = ss[j];
                    float ap = As[p * 37 + k], aq = As[q * 37 + k];
                    As[p * 37 + k] = c * ap - sn * aq;
                    As[q * 37 + k] = sn * ap + c * aq;
                    float vp = Vs[p * 37 + k], vq = Vs[q * 37 + k];
                    Vs[p * 37 + k] = c * vp - sn * vq;
                    Vs[q * 37 + k] = sn * vp + c * vq;
                }
                __syncthreads();
                // column phase: rotate columns of A
                for (int w = tid; w < npairs * ns; w += 64) {
                    int j = w / ns, k = w % ns;
                    int pq = pp[j]; int p = pq >> 8, q = pq & 255;
                    float c = cc[j], sn = ss[j];
                    float ap = As[k * 37 + p], aq = As[k * 37 + q];
                    As[k * 37 + p] = c * ap - sn * aq;
                    As[k * 37 + q] = sn * ap + c * aq;
                }
                __syncthreads();
            }
        }
    }

    for (int i = tid; i < ns; i += 64) lam_out[base + i] = As[i * 37 + i];
    for (int t = tid; t < ns * 128; t += 64)
        Vt_full[(base + t / 128) * 128 + (t & 127)] = 0.f;
    __syncthreads();
    for (int t = tid; t < ns * ns; t += 64) {
        int i = t / ns, j = t % ns;
        Vt_full[(base + i) * 128 + st[j]] = Vs[i * 37 + j];
    }
}

__global__ void k_opv(const float* __restrict__ Vt, float* __restrict__ U) {
    int idx = blockIdx.x * 256 + threadIdx.x;
    int b = idx >> 7, r = idx & 127;
    float acc = 0.f;
#pragma unroll
    for (int p = 0; p < 7; ++p)
        if (!((r >> p) & 1)) acc += Vt[b * 128 + r + (1 << p)];
    U[b * 128 + r] = acc;
}

__global__ void k_m(const float* __restrict__ Vt, const float* __restrict__ U,
                    float* __restrict__ M) {
    __shared__ float va[128];
    int a = blockIdx.x, b = threadIdx.x;
    va[b] = Vt[a * 128 + b];
    __syncthreads();
    float acc = 0.f;
    for (int r = 0; r < 128; ++r) acc += va[r] * U[b * 128 + r];
    M[a * 128 + b] = acc;
}

__global__ void k_w(const float* __restrict__ M, float* __restrict__ W) {
    int idx = blockIdx.x * 256 + threadIdx.x;
    int a = idx >> 7, b = idx & 127;
    W[idx] = M[idx] * 0.5f * (M[idx] + M[b * 128 + a]);
}

// FID[n] = apod(n) * sum_ab W[a][b] e^{+i(lam_a-lam_b) t_n}
__global__ __launch_bounds__(256) void k_fid(const float* __restrict__ W,
                                             const float* __restrict__ lam,
                                             float2* __restrict__ fidf,
                                             float* __restrict__ out) {
    __shared__ float2 cbuf[128];
    __shared__ float  redr[256], redi[256];
    const int n = blockIdx.x;
    const int tid = threadIdx.x;
    const float t = (float)n * DT_F;
    if (tid < 128) {
        float sn, cs;
        sincosf(lam[tid] * t, &sn, &cs);
        cbuf[tid] = make_float2(cs, -sn);
    }
    __syncthreads();
    float ar = 0.f, ai = 0.f;
    for (int i = 0; i < 64; ++i) {
        int m = i * 256 + tid;
        int a = m >> 7, b = m & 127;
        float w = W[m];
        float2 ca = cbuf[a], cb = cbuf[b];
        ar += w * (ca.x * cb.x + ca.y * cb.y);
        ai += w * (ca.x * cb.y - ca.y * cb.x);
    }
    redr[tid] = ar; redi[tid] = ai;
    __syncthreads();
    for (int s = 128; s > 0; s >>= 1) {
        if (tid < s) { redr[tid] += redr[tid + s]; redi[tid] += redi[tid + s]; }
        __syncthreads();
    }
    if (tid == 0) {
        float ap = expf(-(DT_F / T2_F) * (float)n);
        float re = redr[0] * ap, im = redi[0] * ap;
        fidf[n] = make_float2(re, im);
        out[n] = re;
    }
}

// Re of shifted spectrum: out[8192+k] = Re( sum_n FID[n] e^{-2pi i n ((k+4096)&8191)/8192} )
__global__ __launch_bounds__(256) void k_dft(const float2* __restrict__ fidf,
                                             float* __restrict__ out) {
    __shared__ float2 fid[4096];
    const int tid = threadIdx.x;
    for (int m = tid; m < 4096; m += 256) fid[m] = fidf[m];
    __syncthreads();
    const int k = blockIdx.x * 256 + tid;       // 0..8191
    const int K = (k + 4096) & 8191;
    const float C = TWO_PI / 8192.0f;
    float ar = 0.f;
    int idx = 0;
    for (int n = 0; n < 4096; ++n) {
        float2 s = fid[n];
        float sn, cs;
        __sincosf(C * (float)idx, &sn, &cs);
        ar += s.x * cs + s.y * sn;
        idx = (idx + K) & 8191;
    }
    out[8192 + k] = ar;
}

__global__ void k_axes(float* __restrict__ out) {
    int i = blockIdx.x * 256 + threadIdx.x;     // 0..8191
    if (i < N_SAMP)
        out[4096 + i] = (float)i * ((N_SAMP / SW_F) / (float)(N_SAMP - 1));
    if (i < 2 * N_SAMP)
        out[16384 + i] = -0.5f * SW_F + (float)i * (SW_F / (float)(2 * N_SAMP - 1));
}

extern "C" void kernel_launch(void* const* d_in, const int* in_sizes, int n_in,
                              void* d_out, int out_size, void* d_ws, size_t ws_size,
                              hipStream_t stream) {
    const float* h = (const float*)d_in[0];
    float* out = (float*)d_out;
    float* ws  = (float*)d_ws;

    float*  Vt   = ws;
    float*  lam  = ws + 16384;
    float*  U    = ws + 16512;
    float*  M    = ws + 32896;
    float*  W    = ws + 49280;
    float2* fidf = (float2*)(ws + 65664);

    k_eig<<<8, 64, 0, stream>>>(h, Vt, lam);
    k_opv<<<64, 256, 0, stream>>>(Vt, U);
    k_m<<<128, 128, 0, stream>>>(Vt, U, M);
    k_w<<<64, 256, 0, stream>>>(M, W);
    k_fid<<<N_SAMP, 256, 0, stream>>>(W, lam, fidf, out);
    k_dft<<<32, 256, 0, stream>>>(fidf, out);
    k_axes<<<32, 256, 0, stream>>>(out);
}

// Round 12
// 295.890 us; speedup vs baseline: 19.1915x; 3.5014x over previous
//
#include <hip/hip_runtime.h>
#include <math.h>

#define N_SAMP 4096
#define NS     7
#define DT_F   1e-5f
#define B0_F   80.0f
#define T2_F   1.0f
#define SW_F   1000.0f
#define TWO_PI 6.2831853071795864769f
#define NSWEEP_S 8

// ws layout (floats): Vt 0..16384 | lam 16384..16512 | U 16512..32896 |
//                     M 32896..49280 | W 49280..65664 | fidf(float2) 65664..73856 |
//                     part 73856..139392
// out (f32, 24576): ReFID [0,4096) | time [4096,8192) |
//                   Re shifted spec [8192,16384) | freq [16384,24576)

// Sector eigensolver: H0 block-diagonal in popcount sectors, sizes C(7,s).
// One workgroup (704 thr) per sector; static (pair,col) mapping; cyclic Jacobi.
__global__ __launch_bounds__(704) void k_eig(const float* __restrict__ h,
                                             float* __restrict__ Vt_full,
                                             float* __restrict__ lam_out) {
    const int nsz_[8]   = {1, 7, 21, 35, 35, 21, 7, 1};
    const int nbase_[8] = {0, 1, 8, 29, 64, 99, 120, 127};
    const int s    = blockIdx.x;
    const int ns   = nsz_[s];
    const int base = nbase_[s];
    const int tid  = threadIdx.x;

    __shared__ float As[36 * 37];
    __shared__ float Vs[36 * 37];
    __shared__ int   st[36];
    __shared__ float hs[49];
    __shared__ int   pp[18];
    __shared__ float cc[18], ss[18];

    if (tid < 49) hs[tid] = h[tid];
    if (tid == 0) {
        int cnt = 0;
        for (int r = 0; r < 128; ++r) if (__popc(r) == s) st[cnt++] = r;
    }
    for (int t = tid; t < 36 * 37; t += 704) { As[t] = 0.f; Vs[t] = 0.f; }
    __syncthreads();

    for (int t = tid; t < ns * ns; t += 704) {
        int i = t / ns, j = t % ns;      // infrequent; ok
        int r = st[i], c = st[j];
        float val = 0.f;
        if (r == c) {
            float acc = 0.f;
            for (int a = 0; a < 7; ++a) {
                float za = ((r >> (6 - a)) & 1) ? -0.5f : 0.5f;
                acc += B0_F * hs[a * 7 + a] * za;
                for (int b = a + 1; b < 7; ++b) {
                    float zb = ((r >> (6 - b)) & 1) ? -0.5f : 0.5f;
                    acc += hs[a * 7 + b] * za * zb;
                }
            }
            val = TWO_PI * acc;
        } else {
            int x = r ^ c;
            if (__popc(x) == 2) {
                int u = 31 - __clz(x);
                int v = __ffs(x) - 1;
                if (((r >> u) & 1) != ((r >> v) & 1))
                    val = TWO_PI * 0.5f * hs[(6 - u) * 7 + (6 - v)];
            }
        }
        As[i * 37 + j] = val;
    }
    for (int i = tid; i < ns; i += 704) Vs[i * 37 + i] = 1.f;
    __syncthreads();

    if (ns > 1) {
        const int m      = ns + 1;          // all sector sizes odd -> m even
        const int nr     = m - 1;
        const int npairs = m / 2;
        const int jj     = tid / 36;        // compile-time div
        const int kk     = tid - jj * 36;

        for (int sweep = 0; sweep < NSWEEP_S; ++sweep) {
            for (int t = 0; t < nr; ++t) {
                if (tid < npairs) {
                    int p, q;
                    if (tid == 0) { p = t; q = m - 1; }
                    else {
                        int a1 = (t + tid) % nr;
                        int b1 = (t + nr - tid) % nr;
                        p = a1 < b1 ? a1 : b1;
                        q = a1 < b1 ? b1 : a1;
                    }
                    float c = 1.f, sn = 0.f;
                    if (q < ns) {
                        float app = As[p * 37 + p];
                        float aqq = As[q * 37 + q];
                        float apq = As[p * 37 + q];
                        if (fabsf(apq) >= 1e-30f) {
                            float tau = (aqq - app) / (2.f * apq);
                            float tt  = copysignf(1.f / (fabsf(tau) + sqrtf(1.f + tau * tau)), tau);
                            c  = rsqrtf(1.f + tt * tt);
                            sn = tt * c;
                        }
                    }
                    pp[tid] = (p << 8) | q;
                    cc[tid] = c; ss[tid] = sn;
                }
                __syncthreads();
                // row phase: rotate rows of A and V (one shot)
                if (jj < npairs && kk < ns) {
                    int pq = pp[jj]; int p = pq >> 8, q = pq & 255;
                    if (q < ns) {
                        float c = cc[jj], sn = ss[jj];
                        float ap = As[p * 37 + kk], aq = As[q * 37 + kk];
                        As[p * 37 + kk] = c * ap - sn * aq;
                        As[q * 37 + kk] = sn * ap + c * aq;
                        float vp = Vs[p * 37 + kk], vq = Vs[q * 37 + kk];
                        Vs[p * 37 + kk] = c * vp - sn * vq;
                        Vs[q * 37 + kk] = sn * vp + c * vq;
                    }
                }
                __syncthreads();
                // column phase: rotate columns of A (one shot)
                if (jj < npairs && kk < ns) {
                    int pq = pp[jj]; int p = pq >> 8, q = pq & 255;
                    if (q < ns) {
                        float c = cc[jj], sn = ss[jj];
                        float ap = As[kk * 37 + p], aq = As[kk * 37 + q];
                        As[kk * 37 + p] = c * ap - sn * aq;
                        As[kk * 37 + q] = sn * ap + c * aq;
                    }
                }
                __syncthreads();
            }
        }
    }

    for (int i = tid; i < ns; i += 704) lam_out[base + i] = As[i * 37 + i];
    for (int t = tid; t < ns * 128; t += 704)
        Vt_full[(base + t / 128) * 128 + (t & 127)] = 0.f;
    __syncthreads();
    for (int t = tid; t < ns * ns; t += 704) {
        int i = t / ns, j = t % ns;
        Vt_full[(base + i) * 128 + st[j]] = Vs[i * 37 + j];
    }
}

__global__ void k_opv(const float* __restrict__ Vt, float* __restrict__ U) {
    int idx = blockIdx.x * 256 + threadIdx.x;
    int b = idx >> 7, r = idx & 127;
    float acc = 0.f;
#pragma unroll
    for (int p = 0; p < 7; ++p)
        if (!((r >> p) & 1)) acc += Vt[b * 128 + r + (1 << p)];
    U[b * 128 + r] = acc;
}

__global__ void k_m(const float* __restrict__ Vt, const float* __restrict__ U,
                    float* __restrict__ M) {
    __shared__ float va[128];
    int a = blockIdx.x, b = threadIdx.x;
    va[b] = Vt[a * 128 + b];
    __syncthreads();
    float acc = 0.f;
    for (int r = 0; r < 128; ++r) acc += va[r] * U[b * 128 + r];
    M[a * 128 + b] = acc;
}

__global__ void k_w(const float* __restrict__ M, float* __restrict__ W) {
    int idx = blockIdx.x * 256 + threadIdx.x;
    int a = idx >> 7, b = idx & 127;
    W[idx] = M[idx] * 0.5f * (M[idx] + M[b * 128 + a]);
}

// 8 samples per block via phasor recurrence:
// z_m(t0) = e^{+i lam_a t0} e^{-i lam_b t0};  z(t+DT) = z * f_m, f_m = e^{+i lam_a DT} e^{-i lam_b DT}
__global__ __launch_bounds__(256) void k_fid(const float* __restrict__ W,
                                             const float* __restrict__ lam,
                                             float* __restrict__ fidfF,
                                             float* __restrict__ out) {
    __shared__ float2 cb0[128], dd[128];
    __shared__ float  lred[4][16];
    const int n0  = blockIdx.x * 8;
    const int tid = threadIdx.x;
    const float t0 = (float)n0 * DT_F;
    if (tid < 128) {
        float sn, cs;
        sincosf(lam[tid] * t0, &sn, &cs);
        cb0[tid] = make_float2(cs, -sn);        // e^{-i lam t0}
        sincosf(lam[tid] * DT_F, &sn, &cs);
        dd[tid] = make_float2(cs, -sn);         // e^{-i lam DT}
    }
    __syncthreads();

    float ar0=0,ar1=0,ar2=0,ar3=0,ar4=0,ar5=0,ar6=0,ar7=0;
    float ai0=0,ai1=0,ai2=0,ai3=0,ai4=0,ai5=0,ai6=0,ai7=0;
    for (int i = 0; i < 64; ++i) {
        int m = i * 256 + tid;
        int a = m >> 7, b = m & 127;
        float w = W[m];
        float2 ca = cb0[a], cbv = cb0[b];
        float2 da = dd[a],  db  = dd[b];
        // z = conj(ca)*cbv ; f = conj(da)*db
        float zr = ca.x * cbv.x + ca.y * cbv.y;
        float zi = ca.x * cbv.y - ca.y * cbv.x;
        float fr = da.x * db.x + da.y * db.y;
        float fi = da.x * db.y - da.y * db.x;
        ar0 += w * zr; ai0 += w * zi; { float tr = zr*fr - zi*fi; zi = zr*fi + zi*fr; zr = tr; }
        ar1 += w * zr; ai1 += w * zi; { float tr = zr*fr - zi*fi; zi = zr*fi + zi*fr; zr = tr; }
        ar2 += w * zr; ai2 += w * zi; { float tr = zr*fr - zi*fi; zi = zr*fi + zi*fr; zr = tr; }
        ar3 += w * zr; ai3 += w * zi; { float tr = zr*fr - zi*fi; zi = zr*fi + zi*fr; zr = tr; }
        ar4 += w * zr; ai4 += w * zi; { float tr = zr*fr - zi*fi; zi = zr*fi + zi*fr; zr = tr; }
        ar5 += w * zr; ai5 += w * zi; { float tr = zr*fr - zi*fi; zi = zr*fi + zi*fr; zr = tr; }
        ar6 += w * zr; ai6 += w * zi; { float tr = zr*fr - zi*fi; zi = zr*fi + zi*fr; zr = tr; }
        ar7 += w * zr; ai7 += w * zi;
    }

    const int wave = tid >> 6, lane = tid & 63;
    float acc[16] = {ar0,ai0,ar1,ai1,ar2,ai2,ar3,ai3,ar4,ai4,ar5,ai5,ar6,ai6,ar7,ai7};
#pragma unroll 16
    for (int v = 0; v < 16; ++v) {
        float x = acc[v];
        for (int off = 32; off > 0; off >>= 1) x += __shfl_down(x, off);
        if (lane == 0) lred[wave][v] = x;
    }
    __syncthreads();
    if (tid < 16) {
        float x = lred[0][tid] + lred[1][tid] + lred[2][tid] + lred[3][tid];
        int jj = tid >> 1, c = tid & 1;
        int n = n0 + jj;
        float ap = expf(-(DT_F / T2_F) * (float)n);
        x *= ap;
        fidfF[2 * n + c] = x;
        if (c == 0) out[n] = x;
    }
}

// split-K shifted-spectrum partials: 8 chunks x 32 k-groups
__global__ __launch_bounds__(256) void k_dft(const float2* __restrict__ fidf,
                                             float* __restrict__ part) {
    __shared__ float2 fs[512];
    const int tid = threadIdx.x;
    const int ch  = blockIdx.x >> 5;
    const int kb  = blockIdx.x & 31;
    const int n0  = ch * 512;
    fs[tid]       = fidf[n0 + tid];
    fs[tid + 256] = fidf[n0 + tid + 256];
    __syncthreads();
    const int k = kb * 256 + tid;
    const int K = (k + 4096) & 8191;
    const float C = TWO_PI / 8192.0f;
    int idx = (n0 * K) & 8191;
    float ar = 0.f;
    for (int i = 0; i < 512; ++i) {
        float2 s = fs[i];
        float sn, cs;
        __sincosf(C * (float)idx, &sn, &cs);
        ar += s.x * cs + s.y * sn;
        idx = (idx + K) & 8191;
    }
    part[ch * 8192 + k] = ar;
}

__global__ void k_dred(const float* __restrict__ part, float* __restrict__ out) {
    int k = blockIdx.x * 256 + threadIdx.x;   // 0..8191
    float s = 0.f;
#pragma unroll
    for (int ch = 0; ch < 8; ++ch) s += part[ch * 8192 + k];
    out[8192 + k] = s;
}

__global__ void k_axes(float* __restrict__ out) {
    int i = blockIdx.x * 256 + threadIdx.x;     // 0..8191
    if (i < N_SAMP)
        out[4096 + i] = (float)i * ((N_SAMP / SW_F) / (float)(N_SAMP - 1));
    if (i < 2 * N_SAMP)
        out[16384 + i] = -0.5f * SW_F + (float)i * (SW_F / (float)(2 * N_SAMP - 1));
}

extern "C" void kernel_launch(void* const* d_in, const int* in_sizes, int n_in,
                              void* d_out, int out_size, void* d_ws, size_t ws_size,
                              hipStream_t stream) {
    const float* h = (const float*)d_in[0];
    float* out = (float*)d_out;
    float* ws  = (float*)d_ws;

    float*  Vt   = ws;
    float*  lam  = ws + 16384;
    float*  U    = ws + 16512;
    float*  M    = ws + 32896;
    float*  W    = ws + 49280;
    float*  fidfF= ws + 65664;
    float2* fidf = (float2*)(ws + 65664);
    float*  part = ws + 73856;

    k_eig<<<8, 704, 0, stream>>>(h, Vt, lam);
    k_opv<<<64, 256, 0, stream>>>(Vt, U);
    k_m<<<128, 128, 0, stream>>>(Vt, U, M);
    k_w<<<64, 256, 0, stream>>>(M, W);
    k_fid<<<512, 256, 0, stream>>>(W, lam, fidfF, out);
    k_dft<<<256, 256, 0, stream>>>(fidf, part);
    k_dred<<<32, 256, 0, stream>>>(part, out);
    k_axes<<<32, 256, 0, stream>>>(out);
}